// Round 4
// baseline (542.148 us; speedup 1.0000x reference)
//
#include <hip/hip_runtime.h>

#define M_TOK 16384   // B*S = 8*2048
#define K_DIM 1024    // H
#define N_DIM 4096    // I
#define SLABA ((size_t)M_TOK * 64)   // bytes per A k-slab (1 MB)
#define SLABB ((size_t)N_DIM * 64)   // bytes per B k-slab (256 KB)

using i32x4 = __attribute__((ext_vector_type(4))) int;
using f32x4 = __attribute__((ext_vector_type(4))) float;  // clang vector:
// __builtin_nontemporal_* requires a real vector type, not HIP_vector_type.

// IntGELU elementwise. xi = exact integer out_int (|oi| < 2^22 in practice,
// exact in f32). The reference's x/sf round-trip (fl(fl(oi*sf)/sf)) differs
// from oi by ~2^-23 relative; downstream that perturbs q by ~1e-7 relative,
// flipping only exact rint-boundary cases -> stays at the existing 1-LSB
// absmax. The IEEE div it required cost ~9 VALU ops per element.
// pa = (b_int(bias), bias_sf, b_g, c_g) ; pb.x = shift_int, pb.y = sf_out
__device__ __forceinline__ float gelu_q(int acc, float4 pa, float4 pb) {
  float xi = (float)acc + pa.x;      // out_int = einsum + b_int  (exact ints)
  float sgn = (xi > 0.f) ? 1.f : ((xi < 0.f) ? -1.f : 0.f);
  float ab  = fminf(fabsf(xi), -pa.z);
  float tt  = ab + pa.z;
  float yi  = sgn * (tt * tt + pa.w);
  yi = floorf(yi * (1.0f / 16384.0f));   // floor(y / 2^14), exact pow2 scale
  return xi * (yi + pb.x);               // q  (output value = q * pb.y)
}

// ---------- kernel 1: x -> int8, slab-major [k>>6][m][64] ----------
__global__ void k_prep_x(const float* __restrict__ x,
                         const float* __restrict__ sfp,
                         char* __restrict__ x8) {
  float r = 1.0f / sfp[0];
  int i4 = blockIdx.x * 256 + threadIdx.x;          // global float4 index
  f32x4 v = __builtin_nontemporal_load((const f32x4*)x + i4);  // read-once
  int c0 = (int)rintf(v.x * r);
  int c1 = (int)rintf(v.y * r);
  int c2 = (int)rintf(v.z * r);
  int c3 = (int)rintf(v.w * r);
  int packed = (c0 & 0xFF) | ((c1 & 0xFF) << 8) | ((c2 & 0xFF) << 16)
             | ((c3 & 0xFF) << 24);
  int m = i4 >> 8, kq = i4 & 255;                   // kq = float4 within row
  ((int*)(x8 + (size_t)(kq >> 4) * SLABA + (size_t)m * 64))[kq & 15] = packed;
}

// ---------- kernel 2: weight quant (slab-major) + per-channel constants ----
__global__ void k_prep_w(const float* __restrict__ W,
                         const float* __restrict__ bias,
                         const float* __restrict__ sfp,
                         char* __restrict__ w8,
                         float4* __restrict__ cA,
                         float4* __restrict__ cB) {
  const int o = blockIdx.x;
  const int t = threadIdx.x;
  float4 wv = ((const float4*)(W + (size_t)o * K_DIM))[t];   // 256*4 = 1024
  float vmn = fminf(fminf(wv.x, wv.y), fminf(wv.z, wv.w));
  float vmx = fmaxf(fmaxf(wv.x, wv.y), fmaxf(wv.z, wv.w));
#pragma unroll
  for (int off = 32; off; off >>= 1) {
    vmn = fminf(vmn, __shfl_down(vmn, off, 64));
    vmx = fmaxf(vmx, __shfl_down(vmx, off, 64));
  }
  __shared__ float sm[8];
  __shared__ float s_wsf;
  int lane = t & 63, wv_id = t >> 6;
  if (lane == 0) { sm[wv_id] = vmn; sm[4 + wv_id] = vmx; }
  __syncthreads();
  if (t == 0) {
    float mn = fminf(fminf(sm[0], sm[1]), fminf(sm[2], sm[3]));
    float mx = fmaxf(fmaxf(sm[4], sm[5]), fmaxf(sm[6], sm[7]));
    float wsf = fmaxf(fmaxf(fabsf(mn), fabsf(mx)), 1e-8f) / 127.0f;
    s_wsf = wsf;
    float sfin = sfp[0];
    float bsf  = wsf * sfin;                         // bias_sf
    float bint = rintf(bias[o] / bsf);               // b_int
    float sfe  = bsf / 1.4142f;                      // sf / GELU_K
    float bg   = floorf(-1.769f / sfe);              // gelu b_int
    const float C2F = (float)(1.0 / -0.2888);        // C2 computed in double
    float cg   = floorf(C2F / (sfe * sfe));          // gelu c_int
    float sfsig = sfe * sfe * (-0.2888f);
    sfsig = sfsig * 16384.0f;                        // * 2^14
    float shiftint = floorf(1.0f / sfsig);
    float sfout = bsf * sfsig / 2.0f;
    cA[o] = make_float4(bint, bsf, bg, cg);
    cB[o] = make_float4(shiftint, sfout, 0.0f, 0.0f);
  }
  __syncthreads();
  float wsf = s_wsf;
  int q0 = (int)fminf(fmaxf(rintf(wv.x / wsf), -128.f), 127.f);
  int q1 = (int)fminf(fmaxf(rintf(wv.y / wsf), -128.f), 127.f);
  int q2 = (int)fminf(fmaxf(rintf(wv.z / wsf), -128.f), 127.f);
  int q3 = (int)fminf(fmaxf(rintf(wv.w / wsf), -128.f), 127.f);
  int packed = (q0 & 0xFF) | ((q1 & 0xFF) << 8) | ((q2 & 0xFF) << 16)
             | ((q3 & 0xFF) << 24);
  ((int*)(w8 + (size_t)(t >> 4) * SLABB + (size_t)o * 64))[t & 15] = packed;
}

// ---------- kernel 3: int8 GEMM + GELU -> out (q, f32) + per-block minmax --
// 128x128 block tile, 4 waves (2x2), each wave 64x64 via 4x4 of 16x16x64 MFMA.
// Latency fixes this round:
//  * nontemporal epilogue stores: the 256MB q-stream was thrashing L2/L3
//    (FETCH 77MB vs 20MB minimum) and turning main-loop loads into HBM misses.
//  * XCD swizzle: each XCD owns 4 n-strips (B slice 512KB, L2-resident),
//    sweeps m; A strips hit L3 after the first XCD touches them.
//  * manual ping-pong unroll: kills 512 v_mov rotation copies per thread.
__global__ __launch_bounds__(256) void k_gemm(
    const char* __restrict__ A, const char* __restrict__ B,
    const float4* __restrict__ cA, const float4* __restrict__ cB,
    float* __restrict__ out, float2* __restrict__ pmm) {
  const int t = threadIdx.x;
  const int lane = t & 63;
  const int w = t >> 6;
  const int wm = w >> 1, wn = w & 1;

  // XCD-aware swizzle (8 XCDs, lin%8 ~ XCD round-robin). Bijective:
  // (xcd, local&3, local>>2) <-> lin.
  const int lin = blockIdx.y * gridDim.x + blockIdx.x;   // 0..4095
  const int xcd = lin & 7;
  const int local = lin >> 3;                            // 0..511
  const int bx = xcd * 4 + (local & 3);                  // n strip 0..31
  const int by = local >> 2;                             // m strip 0..127
  const int m0 = by * 128;
  const int n0 = bx * 128;

  const int fr = lane & 15;                   // fragment row within 16
  const int loff = fr * 64 + (lane >> 4) * 16;  // lane byte offset in 1KB frag

  const char* Ap = A + (size_t)(m0 + wm * 64) * 64 + loff;
  const char* Bp = B + (size_t)(n0 + wn * 64) * 64 + loff;

  i32x4 acc[4][4] = {};
  i32x4 ax[4], bxr[4], ay[4], byr[4];
#pragma unroll
  for (int i = 0; i < 4; ++i) {
    ax[i]  = *(const i32x4*)(Ap + i * 1024);
    bxr[i] = *(const i32x4*)(Bp + i * 1024);
  }
#pragma unroll
  for (int it = 0; it < K_DIM / 64; it += 2) {
    // prefetch slab it+1 -> Y   (it <= 14 so it+1 always valid)
#pragma unroll
    for (int i = 0; i < 4; ++i) {
      ay[i]  = *(const i32x4*)(Ap + (size_t)(it + 1) * SLABA + i * 1024);
      byr[i] = *(const i32x4*)(Bp + (size_t)(it + 1) * SLABB + i * 1024);
    }
#pragma unroll
    for (int mi = 0; mi < 4; ++mi)
#pragma unroll
      for (int ni = 0; ni < 4; ++ni)
        acc[mi][ni] = __builtin_amdgcn_mfma_i32_16x16x64_i8(
            ax[mi], bxr[ni], acc[mi][ni], 0, 0, 0);
    if (it + 2 < K_DIM / 64) {
#pragma unroll
      for (int i = 0; i < 4; ++i) {
        ax[i]  = *(const i32x4*)(Ap + (size_t)(it + 2) * SLABA + i * 1024);
        bxr[i] = *(const i32x4*)(Bp + (size_t)(it + 2) * SLABB + i * 1024);
      }
    }
#pragma unroll
    for (int mi = 0; mi < 4; ++mi)
#pragma unroll
      for (int ni = 0; ni < 4; ++ni)
        acc[mi][ni] = __builtin_amdgcn_mfma_i32_16x16x64_i8(
            ay[mi], byr[ni], acc[mi][ni], 0, 0, 0);
  }

  // epilogue: C/D layout col = lane&15, row = (lane>>4)*4 + reg
  const int rowb = m0 + wm * 64 + (lane >> 4) * 4;
  const int colb = n0 + wn * 64 + fr;
  float vmin = 3.4e38f, vmax = -3.4e38f;

#pragma unroll
  for (int ni = 0; ni < 4; ++ni) {
    const int col = colb + ni * 16;
    const float4 pa = cA[col];
    const float4 pb = cB[col];
    float qmn = 3.4e38f, qmx = -3.4e38f;
#pragma unroll
    for (int mi = 0; mi < 4; ++mi) {
#pragma unroll
      for (int r = 0; r < 4; ++r) {
        float q = gelu_q(acc[mi][ni][r], pa, pb);
        qmn = fminf(qmn, q);
        qmx = fmaxf(qmx, q);
        __builtin_nontemporal_store(
            q, &out[(size_t)(rowb + mi * 16 + r) * N_DIM + col]);
      }
    }
    // fold to value-space once per ni (pb.y sign handled robustly)
    float xa = qmn * pb.y, xb = qmx * pb.y;
    vmin = fminf(vmin, fminf(xa, xb));
    vmax = fmaxf(vmax, fmaxf(xa, xb));
  }

#pragma unroll
  for (int off = 32; off; off >>= 1) {
    vmin = fminf(vmin, __shfl_down(vmin, off, 64));
    vmax = fmaxf(vmax, __shfl_down(vmax, off, 64));
  }
  __shared__ float swmn[4], swmx[4];
  if (lane == 0) { swmn[w] = vmin; swmx[w] = vmax; }
  __syncthreads();
  if (t == 0) {
    float bmn = fminf(fminf(swmn[0], swmn[1]), fminf(swmn[2], swmn[3]));
    float bmx = fmaxf(fmaxf(swmx[0], swmx[1]), fmaxf(swmx[2], swmx[3]));
    pmm[lin] = make_float2(bmn, bmx);
  }
}

// ---------- kernel 4: scalar sf + folded requant scale per channel ----------
__global__ void k_scalar(const float2* __restrict__ pmm,
                         const float4* __restrict__ cB,
                         float* __restrict__ cR,
                         float* __restrict__ sfws,
                         float* __restrict__ out_sf) {
  const int t = threadIdx.x;
  float mn = 3.4e38f, mx = -3.4e38f;
  for (int i = t; i < 4096; i += 256) {
    float2 p = pmm[i];
    mn = fminf(mn, p.x);
    mx = fmaxf(mx, p.y);
  }
#pragma unroll
  for (int off = 32; off; off >>= 1) {
    mn = fminf(mn, __shfl_down(mn, off, 64));
    mx = fmaxf(mx, __shfl_down(mx, off, 64));
  }
  __shared__ float sm[8];
  __shared__ float s_sf;
  int lane = t & 63, wid = t >> 6;
  if (lane == 0) { sm[wid] = mn; sm[4 + wid] = mx; }
  __syncthreads();
  if (t == 0) {
    float m0 = fminf(fminf(sm[0], sm[1]), fminf(sm[2], sm[3]));
    float m1 = fmaxf(fmaxf(sm[4], sm[5]), fmaxf(sm[6], sm[7]));
    float sf = fmaxf(fmaxf(fabsf(m0), fabsf(m1)), 1e-8f) / 127.0f;
    s_sf = sf;
    if (blockIdx.x == 0) { sfws[0] = sf; out_sf[0] = sf; }
  }
  __syncthreads();
  float sf = s_sf;
  int o = blockIdx.x * 256 + t;
  float psf = cB[o].y;
  int e;
  float mm = frexpf(psf / sf, &e);        // frexp(pre_sf / sf)
  float mi = rintf(mm * 2147483648.0f);   // m_int = round(m * 2^31)
  cR[o] = mi * ldexpf(1.0f, e - 31);
}

// ---------- kernel 5: in-place requantization of d_out (pure stream) -------
// Grid-stride, nontemporal both directions (no reuse either side).
__global__ __launch_bounds__(256) void k_requant(
    float* __restrict__ out, const float* __restrict__ cR,
    const float* __restrict__ sfws) {
  const float sf = sfws[0];
  const size_t n4 = (size_t)M_TOK * N_DIM / 4;
  for (size_t i4 = (size_t)blockIdx.x * 256 + threadIdx.x; i4 < n4;
       i4 += (size_t)gridDim.x * 256) {
    f32x4 v = __builtin_nontemporal_load((const f32x4*)out + i4);
    int col4 = (int)(i4 & (N_DIM / 4 - 1));
    float4 c = ((const float4*)cR)[col4];
    v.x = fminf(fmaxf(rintf(rintf(v.x) * c.x), -128.f), 127.f) * sf;
    v.y = fminf(fmaxf(rintf(rintf(v.y) * c.y), -128.f), 127.f) * sf;
    v.z = fminf(fmaxf(rintf(rintf(v.z) * c.z), -128.f), 127.f) * sf;
    v.w = fminf(fmaxf(rintf(rintf(v.w) * c.w), -128.f), 127.f) * sf;
    __builtin_nontemporal_store(v, (f32x4*)out + i4);
  }
}

// ---------- launch ----------
extern "C" void kernel_launch(void* const* d_in, const int* in_sizes, int n_in,
                              void* d_out, int out_size, void* d_ws, size_t ws_size,
                              hipStream_t stream) {
  const float* x    = (const float*)d_in[0];
  const float* sfp  = (const float*)d_in[1];
  const float* W    = (const float*)d_in[2];
  const float* bias = (const float*)d_in[3];
  float* out = (float*)d_out;

  char* ws = (char*)d_ws;
  char* x8 = ws;                                                    // 16 MB
  char* w8 = ws + (size_t)M_TOK * K_DIM;                            // 4 MB
  char* tail = ws + (size_t)M_TOK * K_DIM + (size_t)N_DIM * K_DIM;
  float4* cA = (float4*)tail;                                       // 64 KB
  float4* cB = (float4*)(tail + (size_t)N_DIM * 16);                // 64 KB
  float* cR  = (float*)(tail + (size_t)N_DIM * 32);                 // 16 KB
  float2* pmm = (float2*)(tail + (size_t)N_DIM * 36);               // 32 KB
  float* sfws = (float*)(tail + (size_t)N_DIM * 36 + 32768);

  k_prep_x<<<(M_TOK * K_DIM / 4) / 256, 256, 0, stream>>>(x, sfp, x8);
  k_prep_w<<<N_DIM, 256, 0, stream>>>(W, bias, sfp, w8, cA, cB);
  k_gemm<<<dim3(N_DIM / 128, M_TOK / 128), 256, 0, stream>>>(
      x8, w8, cA, cB, out, pmm);
  k_scalar<<<N_DIM / 256, 256, 0, stream>>>(pmm, cB, cR, sfws,
                                            out + (size_t)M_TOK * N_DIM);
  k_requant<<<8192, 256, 0, stream>>>(out, cR, sfws);
}

// Round 5
// 485.077 us; speedup vs baseline: 1.1177x; 1.1177x over previous
//
#include <hip/hip_runtime.h>

#define M_TOK 16384   // B*S = 8*2048
#define K_DIM 1024    // H
#define N_DIM 4096    // I
#define SLABA ((size_t)M_TOK * 64)   // bytes per A k-slab (1 MB)
#define SLABB ((size_t)N_DIM * 64)   // bytes per B k-slab (256 KB)

using i32x4 = __attribute__((ext_vector_type(4))) int;
using f32x4 = __attribute__((ext_vector_type(4))) float;  // clang vector:
// __builtin_nontemporal_* requires a real vector type, not HIP_vector_type.

// async global->LDS, 16B per lane. LDS dest is WAVE-UNIFORM base (+lane*16 by
// HW); global src is per-lane.
__device__ __forceinline__ void gld16(char* lds, const char* g) {
  __builtin_amdgcn_global_load_lds(
      (const __attribute__((address_space(1))) void*)g,
      (__attribute__((address_space(3))) void*)lds, 16, 0, 0);
}

// IntGELU elementwise. xi = exact integer out_int (exact in f32).
// pa = (b_int(bias), bias_sf, b_g, c_g) ; pb.x = shift_int, pb.y = sf_out
__device__ __forceinline__ float gelu_q(int acc, float4 pa, float4 pb) {
  float xi = (float)acc + pa.x;      // out_int = einsum + b_int  (exact ints)
  float sgn = (xi > 0.f) ? 1.f : ((xi < 0.f) ? -1.f : 0.f);
  float ab  = fminf(fabsf(xi), -pa.z);
  float tt  = ab + pa.z;
  float yi  = sgn * (tt * tt + pa.w);
  yi = floorf(yi * (1.0f / 16384.0f));   // floor(y / 2^14), exact pow2 scale
  return xi * (yi + pb.x);               // q  (output value = q * pb.y)
}

// ---------- kernel 1: x -> int8, slab-major [k>>6][m][64] ----------
__global__ void k_prep_x(const float* __restrict__ x,
                         const float* __restrict__ sfp,
                         char* __restrict__ x8) {
  float r = 1.0f / sfp[0];
  int i4 = blockIdx.x * 256 + threadIdx.x;          // global float4 index
  f32x4 v = __builtin_nontemporal_load((const f32x4*)x + i4);  // read-once
  int c0 = (int)rintf(v.x * r);
  int c1 = (int)rintf(v.y * r);
  int c2 = (int)rintf(v.z * r);
  int c3 = (int)rintf(v.w * r);
  int packed = (c0 & 0xFF) | ((c1 & 0xFF) << 8) | ((c2 & 0xFF) << 16)
             | ((c3 & 0xFF) << 24);
  int m = i4 >> 8, kq = i4 & 255;                   // kq = float4 within row
  ((int*)(x8 + (size_t)(kq >> 4) * SLABA + (size_t)m * 64))[kq & 15] = packed;
}

// ---------- kernel 2: weight quant (slab-major) + per-channel constants ----
__global__ void k_prep_w(const float* __restrict__ W,
                         const float* __restrict__ bias,
                         const float* __restrict__ sfp,
                         char* __restrict__ w8,
                         float4* __restrict__ cA,
                         float4* __restrict__ cB) {
  const int o = blockIdx.x;
  const int t = threadIdx.x;
  float4 wv = ((const float4*)(W + (size_t)o * K_DIM))[t];   // 256*4 = 1024
  float vmn = fminf(fminf(wv.x, wv.y), fminf(wv.z, wv.w));
  float vmx = fmaxf(fmaxf(wv.x, wv.y), fmaxf(wv.z, wv.w));
#pragma unroll
  for (int off = 32; off; off >>= 1) {
    vmn = fminf(vmn, __shfl_down(vmn, off, 64));
    vmx = fmaxf(vmx, __shfl_down(vmx, off, 64));
  }
  __shared__ float sm[8];
  __shared__ float s_wsf;
  int lane = t & 63, wv_id = t >> 6;
  if (lane == 0) { sm[wv_id] = vmn; sm[4 + wv_id] = vmx; }
  __syncthreads();
  if (t == 0) {
    float mn = fminf(fminf(sm[0], sm[1]), fminf(sm[2], sm[3]));
    float mx = fmaxf(fmaxf(sm[4], sm[5]), fmaxf(sm[6], sm[7]));
    float wsf = fmaxf(fmaxf(fabsf(mn), fabsf(mx)), 1e-8f) / 127.0f;
    s_wsf = wsf;
    float sfin = sfp[0];
    float bsf  = wsf * sfin;                         // bias_sf
    float bint = rintf(bias[o] / bsf);               // b_int
    float sfe  = bsf / 1.4142f;                      // sf / GELU_K
    float bg   = floorf(-1.769f / sfe);              // gelu b_int
    const float C2F = (float)(1.0 / -0.2888);        // C2 computed in double
    float cg   = floorf(C2F / (sfe * sfe));          // gelu c_int
    float sfsig = sfe * sfe * (-0.2888f);
    sfsig = sfsig * 16384.0f;                        // * 2^14
    float shiftint = floorf(1.0f / sfsig);
    float sfout = bsf * sfsig / 2.0f;
    cA[o] = make_float4(bint, bsf, bg, cg);
    cB[o] = make_float4(shiftint, sfout, 0.0f, 0.0f);
  }
  __syncthreads();
  float wsf = s_wsf;
  int q0 = (int)fminf(fmaxf(rintf(wv.x / wsf), -128.f), 127.f);
  int q1 = (int)fminf(fmaxf(rintf(wv.y / wsf), -128.f), 127.f);
  int q2 = (int)fminf(fmaxf(rintf(wv.z / wsf), -128.f), 127.f);
  int q3 = (int)fminf(fmaxf(rintf(wv.w / wsf), -128.f), 127.f);
  int packed = (q0 & 0xFF) | ((q1 & 0xFF) << 8) | ((q2 & 0xFF) << 16)
             | ((q3 & 0xFF) << 24);
  ((int*)(w8 + (size_t)(t >> 4) * SLABB + (size_t)o * 64))[t & 15] = packed;
}

// ---------- kernel 3: int8 GEMM + GELU -> out (q, f32) + per-block minmax --
// m97 structure: 128x128 tile, 4 waves (2x2), LDS double-buffered K-slabs
// staged with global_load_lds (16B/lane). Each byte of A/B is fetched from
// global ONCE PER BLOCK (was: once per wave, 2.1 GB of load requests) and the
// stage of slab t+1 overlaps the MFMA of slab t. Previous reg-direct pipeline
// was latency-bound and invariant at ~170-177us across VALU/occupancy changes.
__global__ __launch_bounds__(256) void k_gemm(
    const char* __restrict__ A, const char* __restrict__ B,
    const float4* __restrict__ cA, const float4* __restrict__ cB,
    float* __restrict__ out, float2* __restrict__ pmm) {
  const int t = threadIdx.x;
  const int lane = t & 63;
  const int w = t >> 6;
  const int wm = w >> 1, wn = w & 1;

  // XCD-aware swizzle (8 XCDs). Bijective: (lin&7, (lin>>3)&3, lin>>5).
  const int lin = blockIdx.y * gridDim.x + blockIdx.x;   // 0..4095
  const int xcd = lin & 7;
  const int local = lin >> 3;                            // 0..511
  const int bx = xcd * 4 + (local & 3);                  // n strip 0..31
  const int by = local >> 2;                             // m strip 0..127
  const int m0 = by * 128;
  const int n0 = bx * 128;

  const int fr = lane & 15;                    // fragment row within 16
  const int hi16 = (lane >> 4) * 16;           // k-chunk byte offset

  __shared__ char Ab[2][8192];                 // 128 rows x 64 B
  __shared__ char Bb[2][8192];

  // per-thread LDS fragment byte offsets (row*64 + k-chunk)
  int aoff[4], boff[4];
#pragma unroll
  for (int i = 0; i < 4; ++i) {
    aoff[i] = (wm * 64 + i * 16 + fr) * 64 + hi16;
    boff[i] = (wn * 64 + i * 16 + fr) * 64 + hi16;
  }

  const char* Abase = A + (size_t)m0 * 64;     // + slab*SLABA (contig 8 KB)
  const char* Bbase = B + (size_t)n0 * 64;     // + slab*SLABB (contig 8 KB)
  const int c0 = w * 1024 + lane * 16;         // this wave's 1KB chunk 0
  const int c1 = (w + 4) * 1024 + lane * 16;   // this wave's 1KB chunk 1
  const int l0 = w * 1024, l1 = (w + 4) * 1024;  // uniform LDS bases

  // prologue: stage slab 0 into buffer 0
  {
    const char* As = Abase;
    const char* Bs = Bbase;
    gld16(&Ab[0][l0], As + c0);
    gld16(&Ab[0][l1], As + c1);
    gld16(&Bb[0][l0], Bs + c0);
    gld16(&Bb[0][l1], Bs + c1);
  }
  __syncthreads();

  i32x4 acc[4][4] = {};
  for (int it = 0; it < K_DIM / 64; ++it) {
    const int cur = it & 1;
    if (it + 1 < K_DIM / 64) {               // stage slab it+1 -> other buf
      const char* As = Abase + (size_t)(it + 1) * SLABA;
      const char* Bs = Bbase + (size_t)(it + 1) * SLABB;
      gld16(&Ab[cur ^ 1][l0], As + c0);
      gld16(&Ab[cur ^ 1][l1], As + c1);
      gld16(&Bb[cur ^ 1][l0], Bs + c0);
      gld16(&Bb[cur ^ 1][l1], Bs + c1);
    }
    i32x4 af[4], bf[4];
#pragma unroll
    for (int i = 0; i < 4; ++i) {
      af[i] = *(const i32x4*)(&Ab[cur][aoff[i]]);
      bf[i] = *(const i32x4*)(&Bb[cur][boff[i]]);
    }
#pragma unroll
    for (int mi = 0; mi < 4; ++mi)
#pragma unroll
      for (int ni = 0; ni < 4; ++ni)
        acc[mi][ni] = __builtin_amdgcn_mfma_i32_16x16x64_i8(
            af[mi], bf[ni], acc[mi][ni], 0, 0, 0);
    __syncthreads();   // drains staging vmcnt + lds reads, flips buffers
  }

  // epilogue: C/D layout col = lane&15, row = (lane>>4)*4 + reg
  const int rowb = m0 + wm * 64 + (lane >> 4) * 4;
  const int colb = n0 + wn * 64 + fr;
  float vmin = 3.4e38f, vmax = -3.4e38f;

#pragma unroll
  for (int ni = 0; ni < 4; ++ni) {
    const int col = colb + ni * 16;
    const float4 pa = cA[col];
    const float4 pb = cB[col];
    float qmn = 3.4e38f, qmx = -3.4e38f;
#pragma unroll
    for (int mi = 0; mi < 4; ++mi) {
#pragma unroll
      for (int r = 0; r < 4; ++r) {
        float q = gelu_q(acc[mi][ni][r], pa, pb);
        qmn = fminf(qmn, q);
        qmx = fmaxf(qmx, q);
        __builtin_nontemporal_store(
            q, &out[(size_t)(rowb + mi * 16 + r) * N_DIM + col]);
      }
    }
    // fold to value-space once per ni (pb.y sign handled robustly)
    float xa = qmn * pb.y, xb = qmx * pb.y;
    vmin = fminf(vmin, fminf(xa, xb));
    vmax = fmaxf(vmax, fmaxf(xa, xb));
  }

#pragma unroll
  for (int off = 32; off; off >>= 1) {
    vmin = fminf(vmin, __shfl_down(vmin, off, 64));
    vmax = fmaxf(vmax, __shfl_down(vmax, off, 64));
  }
  __shared__ float swmn[4], swmx[4];
  if (lane == 0) { swmn[w] = vmin; swmx[w] = vmax; }
  __syncthreads();
  if (t == 0) {
    float bmn = fminf(fminf(swmn[0], swmn[1]), fminf(swmn[2], swmn[3]));
    float bmx = fmaxf(fmaxf(swmx[0], swmx[1]), fmaxf(swmx[2], swmx[3]));
    pmm[lin] = make_float2(bmn, bmx);
  }
}

// ---------- kernel 4: scalar sf + folded requant scale per channel ----------
__global__ void k_scalar(const float2* __restrict__ pmm,
                         const float4* __restrict__ cB,
                         float* __restrict__ cR,
                         float* __restrict__ sfws,
                         float* __restrict__ out_sf) {
  const int t = threadIdx.x;
  float mn = 3.4e38f, mx = -3.4e38f;
  for (int i = t; i < 4096; i += 256) {
    float2 p = pmm[i];
    mn = fminf(mn, p.x);
    mx = fmaxf(mx, p.y);
  }
#pragma unroll
  for (int off = 32; off; off >>= 1) {
    mn = fminf(mn, __shfl_down(mn, off, 64));
    mx = fmaxf(mx, __shfl_down(mx, off, 64));
  }
  __shared__ float sm[8];
  __shared__ float s_sf;
  int lane = t & 63, wid = t >> 6;
  if (lane == 0) { sm[wid] = mn; sm[4 + wid] = mx; }
  __syncthreads();
  if (t == 0) {
    float m0 = fminf(fminf(sm[0], sm[1]), fminf(sm[2], sm[3]));
    float m1 = fmaxf(fmaxf(sm[4], sm[5]), fmaxf(sm[6], sm[7]));
    float sf = fmaxf(fmaxf(fabsf(m0), fabsf(m1)), 1e-8f) / 127.0f;
    s_sf = sf;
    if (blockIdx.x == 0) { sfws[0] = sf; out_sf[0] = sf; }
  }
  __syncthreads();
  float sf = s_sf;
  int o = blockIdx.x * 256 + t;
  float psf = cB[o].y;
  int e;
  float mm = frexpf(psf / sf, &e);        // frexp(pre_sf / sf)
  float mi = rintf(mm * 2147483648.0f);   // m_int = round(m * 2^31)
  cR[o] = mi * ldexpf(1.0f, e - 31);
}

// ---------- kernel 5: in-place requantization of d_out (pure stream) -------
// Grid-stride, nontemporal both directions (no reuse either side).
__global__ __launch_bounds__(256) void k_requant(
    float* __restrict__ out, const float* __restrict__ cR,
    const float* __restrict__ sfws) {
  const float sf = sfws[0];
  const size_t n4 = (size_t)M_TOK * N_DIM / 4;
  for (size_t i4 = (size_t)blockIdx.x * 256 + threadIdx.x; i4 < n4;
       i4 += (size_t)gridDim.x * 256) {
    f32x4 v = __builtin_nontemporal_load((const f32x4*)out + i4);
    int col4 = (int)(i4 & (N_DIM / 4 - 1));
    float4 c = ((const float4*)cR)[col4];
    v.x = fminf(fmaxf(rintf(rintf(v.x) * c.x), -128.f), 127.f) * sf;
    v.y = fminf(fmaxf(rintf(rintf(v.y) * c.y), -128.f), 127.f) * sf;
    v.z = fminf(fmaxf(rintf(rintf(v.z) * c.z), -128.f), 127.f) * sf;
    v.w = fminf(fmaxf(rintf(rintf(v.w) * c.w), -128.f), 127.f) * sf;
    __builtin_nontemporal_store(v, (f32x4*)out + i4);
  }
}

// ---------- launch ----------
extern "C" void kernel_launch(void* const* d_in, const int* in_sizes, int n_in,
                              void* d_out, int out_size, void* d_ws, size_t ws_size,
                              hipStream_t stream) {
  const float* x    = (const float*)d_in[0];
  const float* sfp  = (const float*)d_in[1];
  const float* W    = (const float*)d_in[2];
  const float* bias = (const float*)d_in[3];
  float* out = (float*)d_out;

  char* ws = (char*)d_ws;
  char* x8 = ws;                                                    // 16 MB
  char* w8 = ws + (size_t)M_TOK * K_DIM;                            // 4 MB
  char* tail = ws + (size_t)M_TOK * K_DIM + (size_t)N_DIM * K_DIM;
  float4* cA = (float4*)tail;                                       // 64 KB
  float4* cB = (float4*)(tail + (size_t)N_DIM * 16);                // 64 KB
  float* cR  = (float*)(tail + (size_t)N_DIM * 32);                 // 16 KB
  float2* pmm = (float2*)(tail + (size_t)N_DIM * 36);               // 32 KB
  float* sfws = (float*)(tail + (size_t)N_DIM * 36 + 32768);

  k_prep_x<<<(M_TOK * K_DIM / 4) / 256, 256, 0, stream>>>(x, sfp, x8);
  k_prep_w<<<N_DIM, 256, 0, stream>>>(W, bias, sfp, w8, cA, cB);
  k_gemm<<<dim3(N_DIM / 128, M_TOK / 128), 256, 0, stream>>>(
      x8, w8, cA, cB, out, pmm);
  k_scalar<<<N_DIM / 256, 256, 0, stream>>>(pmm, cB, cR, sfws,
                                            out + (size_t)M_TOK * N_DIM);
  k_requant<<<8192, 256, 0, stream>>>(out, cR, sfws);
}